// Round 1
// baseline (363.464 us; speedup 1.0000x reference)
//
#include <hip/hip_runtime.h>
#include <hip/hip_bf16.h>

// Problem constants: B=2, S=2048, D=1024, H=16, DH=64
typedef unsigned short u16;
typedef __attribute__((ext_vector_type(8))) short short8;
typedef __attribute__((ext_vector_type(4))) float f32x4;
typedef __attribute__((ext_vector_type(4))) u16 u16x4;

__device__ __forceinline__ u16 f2bf(float f) {
  unsigned u = __builtin_bit_cast(unsigned, f);
  u = (u + 0x7FFFu + ((u >> 16) & 1u)) >> 16;  // RNE
  return (u16)u;
}

__global__ __launch_bounds__(256) void f32_to_bf16(const float* __restrict__ src,
                                                   u16* __restrict__ dst, int n4) {
  int i = blockIdx.x * 256 + threadIdx.x;
  if (i >= n4) return;
  const float4 v = reinterpret_cast<const float4*>(src)[i];
  u16x4 o = { f2bf(v.x), f2bf(v.y), f2bf(v.z), f2bf(v.w) };
  *reinterpret_cast<u16x4*>(dst + (size_t)i * 4) = o;
}

// C = A[M,K] @ W[N,K]^T (bf16 in, fp32 acc). 128x128 tile, BK=32, 4 waves (2x2),
// each wave 64x64 = 4x4 frags of 16x16x32 MFMA.
// MODE 0: out bf16 [B,H,S,DH] (Q/K heads-split)
// MODE 2: +bias, out bf16 [B,H,DH,S] (V transposed)
// MODE 3: +bias, ReLU, out bf16 [M,N]
// MODE 4: +bias, +resid fp32, out fp32 [M,N]
template<int MODE>
__global__ __launch_bounds__(256) void gemm_bt(
    const u16* __restrict__ A, const u16* __restrict__ W,
    const float* __restrict__ bias, const float* __restrict__ resid,
    void* __restrict__ outp, int M, int N, int K)
{
  __shared__ __align__(16) u16 At[128 * 32];
  __shared__ __align__(16) u16 Bt[128 * 32];
  const int tid = threadIdx.x;
  const int lane = tid & 63;
  const int g = lane >> 4, c = lane & 15;
  const int wid = tid >> 6;
  const int wr = (wid >> 1) * 64, wc = (wid & 1) * 64;
  const int m0 = blockIdx.y * 128, n0 = blockIdx.x * 128;
  const int srow = tid >> 2;           // 0..63
  const int scol = (tid & 3) * 8;      // 0,8,16,24

  f32x4 acc[4][4];
  #pragma unroll
  for (int i = 0; i < 4; i++)
    #pragma unroll
    for (int j = 0; j < 4; j++)
      acc[i][j] = (f32x4){0.f, 0.f, 0.f, 0.f};

  const u16* Ab = A + (size_t)m0 * K;
  const u16* Wb = W + (size_t)n0 * K;

  for (int k0 = 0; k0 < K; k0 += 32) {
    short8 a0 = *reinterpret_cast<const short8*>(Ab + (size_t)srow * K + k0 + scol);
    short8 a1 = *reinterpret_cast<const short8*>(Ab + (size_t)(srow + 64) * K + k0 + scol);
    short8 b0 = *reinterpret_cast<const short8*>(Wb + (size_t)srow * K + k0 + scol);
    short8 b1 = *reinterpret_cast<const short8*>(Wb + (size_t)(srow + 64) * K + k0 + scol);
    __syncthreads();  // previous iteration's frag reads complete
    *reinterpret_cast<short8*>(&At[srow * 32 + scol]) = a0;
    *reinterpret_cast<short8*>(&At[(srow + 64) * 32 + scol]) = a1;
    *reinterpret_cast<short8*>(&Bt[srow * 32 + scol]) = b0;
    *reinterpret_cast<short8*>(&Bt[(srow + 64) * 32 + scol]) = b1;
    __syncthreads();
    short8 af[4], bw[4];
    #pragma unroll
    for (int i = 0; i < 4; i++)
      af[i] = *reinterpret_cast<const short8*>(&At[(wr + i * 16 + c) * 32 + g * 8]);
    #pragma unroll
    for (int j = 0; j < 4; j++)
      bw[j] = *reinterpret_cast<const short8*>(&Bt[(wc + j * 16 + c) * 32 + g * 8]);
    #pragma unroll
    for (int i = 0; i < 4; i++)
      #pragma unroll
      for (int j = 0; j < 4; j++)
        acc[i][j] = __builtin_amdgcn_mfma_f32_16x16x32_bf16(af[i], bw[j], acc[i][j], 0, 0, 0);
  }

  #pragma unroll
  for (int i = 0; i < 4; i++) {
    #pragma unroll
    for (int j = 0; j < 4; j++) {
      const int n = n0 + wc + j * 16 + c;
      const float bval = (MODE == 0) ? 0.f : bias[n];
      const int mb = m0 + wr + i * 16 + g * 4;   // first of 4 consecutive rows
      if (MODE == 2) {
        const int bb = mb >> 11, s = mb & 2047, h = n >> 6, d = n & 63;
        u16x4 o;
        #pragma unroll
        for (int r = 0; r < 4; r++) o[r] = f2bf(acc[i][j][r] + bval);
        *reinterpret_cast<u16x4*>(reinterpret_cast<u16*>(outp) +
            ((size_t)((bb << 4) + h) * 64 + d) * 2048 + s) = o;
      } else {
        #pragma unroll
        for (int r = 0; r < 4; r++) {
          const int m = mb + r;
          float v = acc[i][j][r] + bval;
          if (MODE == 0) {
            const int bb = m >> 11, s = m & 2047, h = n >> 6, d = n & 63;
            reinterpret_cast<u16*>(outp)[((size_t)((bb << 4) + h) * 2048 + s) * 64 + d] = f2bf(v);
          } else if (MODE == 3) {
            v = fmaxf(v, 0.f);
            reinterpret_cast<u16*>(outp)[(size_t)m * N + n] = f2bf(v);
          } else {
            v += resid[(size_t)m * N + n];
            reinterpret_cast<float*>(outp)[(size_t)m * N + n] = v;
          }
        }
      }
    }
  }
}

// Flash attention: grid (S/64, B*H), 4 waves/block, each wave owns 16 q-rows.
// Q frags in registers; K tile [32][64] + Vt tile [64][32] staged in LDS per iter.
__global__ __launch_bounds__(256) void attn_kernel(
    const u16* __restrict__ Qh, const u16* __restrict__ Kh,
    const u16* __restrict__ Vt, u16* __restrict__ ao)
{
  __shared__ __align__(16) u16 Kt[32 * 64];
  __shared__ __align__(16) u16 Vtile[64 * 32];
  __shared__ __align__(16) u16 Pl[4][16 * 32];

  const int tid = threadIdx.x;
  const int lane = tid & 63, wid = tid >> 6;
  const int g = lane >> 4, c = lane & 15;
  const int qt = blockIdx.x, bh = blockIdx.y;
  const int q0 = qt * 64 + wid * 16;

  // Q A-frags: m = c (q-row), k = g*8+j (+32), contiguous bf16x8
  const u16* qrow = Qh + (size_t)(bh * 2048 + q0 + c) * 64;
  const short8 aq0 = *reinterpret_cast<const short8*>(qrow + g * 8);
  const short8 aq1 = *reinterpret_cast<const short8*>(qrow + 32 + g * 8);

  f32x4 acc[4];
  #pragma unroll
  for (int dt = 0; dt < 4; dt++) acc[dt] = (f32x4){0.f, 0.f, 0.f, 0.f};
  float m_run[4] = {-1e30f, -1e30f, -1e30f, -1e30f};
  float l_run[4] = {0.f, 0.f, 0.f, 0.f};

  const u16* Kb = Kh + (size_t)bh * 2048 * 64;
  const u16* Vb = Vt + (size_t)bh * 64 * 2048;
  const float ksc = 1.44269504f * 0.125f;  // log2(e)/sqrt(64)
  const f32x4 zf = {0.f, 0.f, 0.f, 0.f};

  for (int t0 = 0; t0 < 2048; t0 += 32) {
    // stage K [32][64] (contiguous 4KB) and Vt [64][32] (64 rows of 64B)
    *reinterpret_cast<short8*>(&Kt[tid * 8]) =
        *reinterpret_cast<const short8*>(Kb + (size_t)t0 * 64 + tid * 8);
    *reinterpret_cast<short8*>(&Vtile[(tid >> 2) * 32 + (tid & 3) * 8]) =
        *reinterpret_cast<const short8*>(Vb + (size_t)(tid >> 2) * 2048 + t0 + (tid & 3) * 8);
    __syncthreads();

    // scores: two 16x16 tiles over t, contraction d=64 (2 mfma each)
    short8 bk00 = *reinterpret_cast<const short8*>(&Kt[c * 64 + g * 8]);
    short8 bk01 = *reinterpret_cast<const short8*>(&Kt[c * 64 + 32 + g * 8]);
    f32x4 s0 = __builtin_amdgcn_mfma_f32_16x16x32_bf16(aq0, bk00, zf, 0, 0, 0);
    s0 = __builtin_amdgcn_mfma_f32_16x16x32_bf16(aq1, bk01, s0, 0, 0, 0);
    short8 bk10 = *reinterpret_cast<const short8*>(&Kt[(16 + c) * 64 + g * 8]);
    short8 bk11 = *reinterpret_cast<const short8*>(&Kt[(16 + c) * 64 + 32 + g * 8]);
    f32x4 s1 = __builtin_amdgcn_mfma_f32_16x16x32_bf16(aq0, bk10, zf, 0, 0, 0);
    s1 = __builtin_amdgcn_mfma_f32_16x16x32_bf16(aq1, bk11, s1, 0, 0, 0);

    // online softmax in log2 domain; lane holds rows g*4+r, col c / c+16
    float sa[4], sb[4], mt[4];
    #pragma unroll
    for (int r = 0; r < 4; r++) {
      sa[r] = s0[r] * ksc;
      sb[r] = s1[r] * ksc;
      mt[r] = fmaxf(sa[r], sb[r]);
    }
    #pragma unroll
    for (int mk = 1; mk < 16; mk <<= 1) {
      #pragma unroll
      for (int r = 0; r < 4; r++) mt[r] = fmaxf(mt[r], __shfl_xor(mt[r], mk));
    }
    #pragma unroll
    for (int r = 0; r < 4; r++) {
      const float mnew = fmaxf(m_run[r], mt[r]);
      const float alpha = exp2f(m_run[r] - mnew);
      m_run[r] = mnew;
      const float pa = exp2f(sa[r] - mnew);
      const float pb = exp2f(sb[r] - mnew);
      Pl[wid][(g * 4 + r) * 32 + c] = f2bf(pa);
      Pl[wid][(g * 4 + r) * 32 + 16 + c] = f2bf(pb);
      float ps = pa + pb;
      #pragma unroll
      for (int mk = 1; mk < 16; mk <<= 1) ps += __shfl_xor(ps, mk);
      l_run[r] = l_run[r] * alpha + ps;
      #pragma unroll
      for (int dt = 0; dt < 4; dt++) acc[dt][r] *= alpha;
    }
    __syncthreads();  // P visible (and score phase done before V reads)

    // PV: A = P [16q x 32t] (m=c, k=g*8+j), B = V^T via Vtile [d][t]
    const short8 pfrag = *reinterpret_cast<const short8*>(&Pl[wid][c * 32 + g * 8]);
    #pragma unroll
    for (int dt = 0; dt < 4; dt++) {
      short8 vf = *reinterpret_cast<const short8*>(&Vtile[(dt * 16 + c) * 32 + g * 8]);
      acc[dt] = __builtin_amdgcn_mfma_f32_16x16x32_bf16(pfrag, vf, acc[dt], 0, 0, 0);
    }
    __syncthreads();  // V reads done before next stage overwrites
  }

  float inv[4];
  #pragma unroll
  for (int r = 0; r < 4; r++) inv[r] = 1.0f / l_run[r];
  // ao layout [B,S,D], D index = h*64 + d
  u16* ob = ao + (size_t)(bh >> 4) * 2048 * 1024 + (bh & 15) * 64;
  #pragma unroll
  for (int dt = 0; dt < 4; dt++) {
    #pragma unroll
    for (int r = 0; r < 4; r++) {
      const int q = q0 + g * 4 + r;
      ob[(size_t)q * 1024 + dt * 16 + c] = f2bf(acc[dt][r] * inv[r]);
    }
  }
}

extern "C" void kernel_launch(void* const* d_in, const int* in_sizes, int n_in,
                              void* d_out, int out_size, void* d_ws, size_t ws_size,
                              hipStream_t stream) {
  const float* embed = (const float*)d_in[0];
  const float* Wq = (const float*)d_in[1];
  const float* Wk = (const float*)d_in[2];
  const float* Wv = (const float*)d_in[3];
  const float* bv = (const float*)d_in[4];
  const float* W1 = (const float*)d_in[5];
  const float* b1 = (const float*)d_in[6];
  const float* W2 = (const float*)d_in[7];
  const float* b2 = (const float*)d_in[8];

  char* ws = (char*)d_ws;
  u16* ebf = (u16*)ws;  ws += (size_t)4096 * 1024 * 2;  // embed bf16 [B*S, D]
  u16* wqb = (u16*)ws;  ws += (size_t)1024 * 1024 * 2;
  u16* wkb = (u16*)ws;  ws += (size_t)1024 * 1024 * 2;
  u16* wvb = (u16*)ws;  ws += (size_t)1024 * 1024 * 2;
  u16* w1b = (u16*)ws;  ws += (size_t)2048 * 1024 * 2;
  u16* w2b = (u16*)ws;  ws += (size_t)1024 * 2048 * 2;
  u16* Qh  = (u16*)ws;  ws += (size_t)4096 * 1024 * 2;  // [B,H,S,DH]
  u16* Kh  = (u16*)ws;  ws += (size_t)4096 * 1024 * 2;  // [B,H,S,DH]
  u16* Vt  = (u16*)ws;  ws += (size_t)4096 * 1024 * 2;  // [B,H,DH,S]
  u16* ao  = (u16*)ws;  ws += (size_t)4096 * 1024 * 2;  // attn out bf16 [B*S, D]
  u16* h1  = (u16*)ws;  ws += (size_t)4096 * 2048 * 2;  // FFN hidden bf16 [B*S, 2D]

  auto cvt = [&](const float* s, u16* d, int n) {
    int n4 = n / 4;
    f32_to_bf16<<<dim3((n4 + 255) / 256), dim3(256), 0, stream>>>(s, d, n4);
  };
  cvt(embed, ebf, 4096 * 1024);
  cvt(Wq, wqb, 1024 * 1024);
  cvt(Wk, wkb, 1024 * 1024);
  cvt(Wv, wvb, 1024 * 1024);
  cvt(W1, w1b, 2048 * 1024);
  cvt(W2, w2b, 2048 * 1024);

  dim3 blk(256);
  gemm_bt<0><<<dim3(8, 32), blk, 0, stream>>>(ebf, wqb, nullptr, nullptr, Qh, 4096, 1024, 1024);
  gemm_bt<0><<<dim3(8, 32), blk, 0, stream>>>(ebf, wkb, nullptr, nullptr, Kh, 4096, 1024, 1024);
  gemm_bt<2><<<dim3(8, 32), blk, 0, stream>>>(ebf, wvb, bv, nullptr, Vt, 4096, 1024, 1024);
  attn_kernel<<<dim3(32, 32), blk, 0, stream>>>(Qh, Kh, Vt, ao);
  gemm_bt<3><<<dim3(16, 32), blk, 0, stream>>>(ao, w1b, b1, nullptr, h1, 4096, 2048, 1024);
  gemm_bt<4><<<dim3(8, 32), blk, 0, stream>>>(h1, w2b, b2, embed, d_out, 4096, 1024, 2048);
}

// Round 2
// 257.313 us; speedup vs baseline: 1.4125x; 1.4125x over previous
//
#include <hip/hip_runtime.h>
#include <hip/hip_bf16.h>

// Problem constants: B=2, S=2048, D=1024, H=16, DH=64
typedef unsigned short u16;
typedef __attribute__((ext_vector_type(8))) short short8;
typedef __attribute__((ext_vector_type(4))) short short4v;
typedef __attribute__((ext_vector_type(4))) float f32x4;
typedef __attribute__((ext_vector_type(4))) u16 u16x4;

__device__ __forceinline__ u16 f2bf(float f) {
  unsigned u = __builtin_bit_cast(unsigned, f);
  u = (u + 0x7FFFu + ((u >> 16) & 1u)) >> 16;  // RNE
  return (u16)u;
}

__global__ __launch_bounds__(256) void f32_to_bf16(const float* __restrict__ src,
                                                   u16* __restrict__ dst, int n4) {
  int i = blockIdx.x * 256 + threadIdx.x;
  if (i >= n4) return;
  const float4 v = reinterpret_cast<const float4*>(src)[i];
  u16x4 o = { f2bf(v.x), f2bf(v.y), f2bf(v.z), f2bf(v.w) };
  *reinterpret_cast<u16x4*>(dst + (size_t)i * 4) = o;
}

// C = A[M,K] @ W[N,K]^T (bf16 in, fp32 acc). 128x128 tile, BK=32, 4 waves (2x2).
// LDS tiles XOR-swizzled: 16B chunk ch of row r stored at chunk (ch ^ (r&3)).
// MODE 0: out bf16 [B,H,S,DH] (Q/K heads-split)
// MODE 2: +bias, out bf16 [B,H,DH,S] (V transposed)
// MODE 3: +bias, ReLU, out bf16 [M,N]
// MODE 4: +bias, +resid fp32, out fp32 [M,N]
template<int MODE>
__global__ __launch_bounds__(256) void gemm_bt(
    const u16* __restrict__ A, const u16* __restrict__ W,
    const float* __restrict__ bias, const float* __restrict__ resid,
    void* __restrict__ outp, int M, int N, int K)
{
  __shared__ __align__(16) u16 At[128 * 32];
  __shared__ __align__(16) u16 Bt[128 * 32];
  const int tid = threadIdx.x;
  const int lane = tid & 63;
  const int g = lane >> 4, c = lane & 15;
  const int wid = tid >> 6;
  const int wr = (wid >> 1) * 64, wc = (wid & 1) * 64;
  const int m0 = blockIdx.y * 128, n0 = blockIdx.x * 128;
  const int srow = tid >> 2;                         // 0..63
  const int wsw = ((tid & 3) ^ (srow & 3)) * 8;      // swizzled write chunk
  const int rsw = (g ^ (c & 3)) * 8;                 // swizzled read chunk

  f32x4 acc[4][4];
  #pragma unroll
  for (int i = 0; i < 4; i++)
    #pragma unroll
    for (int j = 0; j < 4; j++)
      acc[i][j] = (f32x4){0.f, 0.f, 0.f, 0.f};

  const u16* Ab = A + (size_t)m0 * K;
  const u16* Wb = W + (size_t)n0 * K;
  const int scol = (tid & 3) * 8;

  for (int k0 = 0; k0 < K; k0 += 32) {
    short8 a0 = *reinterpret_cast<const short8*>(Ab + (size_t)srow * K + k0 + scol);
    short8 a1 = *reinterpret_cast<const short8*>(Ab + (size_t)(srow + 64) * K + k0 + scol);
    short8 b0 = *reinterpret_cast<const short8*>(Wb + (size_t)srow * K + k0 + scol);
    short8 b1 = *reinterpret_cast<const short8*>(Wb + (size_t)(srow + 64) * K + k0 + scol);
    __syncthreads();  // previous iteration's frag reads complete
    *reinterpret_cast<short8*>(&At[srow * 32 + wsw]) = a0;
    *reinterpret_cast<short8*>(&At[(srow + 64) * 32 + wsw]) = a1;
    *reinterpret_cast<short8*>(&Bt[srow * 32 + wsw]) = b0;
    *reinterpret_cast<short8*>(&Bt[(srow + 64) * 32 + wsw]) = b1;
    __syncthreads();
    short8 af[4], bw[4];
    #pragma unroll
    for (int i = 0; i < 4; i++)
      af[i] = *reinterpret_cast<const short8*>(&At[(wr + i * 16 + c) * 32 + rsw]);
    #pragma unroll
    for (int j = 0; j < 4; j++)
      bw[j] = *reinterpret_cast<const short8*>(&Bt[(wc + j * 16 + c) * 32 + rsw]);
    #pragma unroll
    for (int i = 0; i < 4; i++)
      #pragma unroll
      for (int j = 0; j < 4; j++)
        acc[i][j] = __builtin_amdgcn_mfma_f32_16x16x32_bf16(af[i], bw[j], acc[i][j], 0, 0, 0);
  }

  #pragma unroll
  for (int i = 0; i < 4; i++) {
    #pragma unroll
    for (int j = 0; j < 4; j++) {
      const int n = n0 + wc + j * 16 + c;
      const float bval = (MODE == 0) ? 0.f : bias[n];
      const int mb = m0 + wr + i * 16 + g * 4;   // first of 4 consecutive rows
      if (MODE == 2) {
        const int bb = mb >> 11, s = mb & 2047, h = n >> 6, d = n & 63;
        u16x4 o;
        #pragma unroll
        for (int r = 0; r < 4; r++) o[r] = f2bf(acc[i][j][r] + bval);
        *reinterpret_cast<u16x4*>(reinterpret_cast<u16*>(outp) +
            ((size_t)((bb << 4) + h) * 64 + d) * 2048 + s) = o;
      } else {
        #pragma unroll
        for (int r = 0; r < 4; r++) {
          const int m = mb + r;
          float v = acc[i][j][r] + bval;
          if (MODE == 0) {
            const int bb = m >> 11, s = m & 2047, h = n >> 6, d = n & 63;
            reinterpret_cast<u16*>(outp)[((size_t)((bb << 4) + h) * 2048 + s) * 64 + d] = f2bf(v);
          } else if (MODE == 3) {
            v = fmaxf(v, 0.f);
            reinterpret_cast<u16*>(outp)[(size_t)m * N + n] = f2bf(v);
          } else {
            v += resid[(size_t)m * N + n];
            reinterpret_cast<float*>(outp)[(size_t)m * N + n] = v;
          }
        }
      }
    }
  }
}

// Flash attention, swapped-QK^T structure.
// grid (S/128, B*H), 4 waves/block; each wave owns 32 q-rows (2 q-tiles of 16).
// S^T = mfma(K, Q): lane (g,c) holds P[t = g*4+r][q = c] -> softmax per-lane,
// P packs directly into the PV A-frag (k = g*8+j <-> t = j<4 ? g*4+j : 16+g*4+j-4).
// K [64t][64dh] and V^T [64d][64t] staged in LDS with chunk^(row&7) XOR swizzle.
__global__ __launch_bounds__(256) void attn_kernel(
    const u16* __restrict__ Qh, const u16* __restrict__ Kh,
    const u16* __restrict__ Vt, u16* __restrict__ ao)
{
  __shared__ __align__(16) u16 Kt[64 * 64];
  __shared__ __align__(16) u16 Vl[64 * 64];

  const int tid = threadIdx.x;
  const int lane = tid & 63, wid = tid >> 6;
  const int g = lane >> 4, c = lane & 15;
  const int bh = blockIdx.y;
  const int qbase = blockIdx.x * 128 + wid * 32;

  // Q as B-operand: n=q=c, k=dh=g*8+j
  short8 bq[2][2];
  #pragma unroll
  for (int qt = 0; qt < 2; qt++) {
    const u16* qrow = Qh + ((size_t)bh * 2048 + qbase + qt * 16 + c) * 64;
    bq[qt][0] = *reinterpret_cast<const short8*>(qrow + g * 8);
    bq[qt][1] = *reinterpret_cast<const short8*>(qrow + 32 + g * 8);
  }

  f32x4 acc[2][4];
  #pragma unroll
  for (int qt = 0; qt < 2; qt++)
    #pragma unroll
    for (int dt = 0; dt < 4; dt++)
      acc[qt][dt] = (f32x4){0.f, 0.f, 0.f, 0.f};
  float m_run[2] = {-1e30f, -1e30f};
  float l_run[2] = {0.f, 0.f};   // lane-partial row sums (reduced at end)

  const u16* Kb = Kh + (size_t)bh * 2048 * 64;
  const u16* Vb = Vt + (size_t)bh * 64 * 2048;
  const float ksc = 1.44269504f * 0.125f;  // log2(e)/sqrt(64)

  const int srow = tid >> 2;        // staging row 0..63
  const int sch = tid & 3;          // staging chunks sch, sch+4
  const int swz = srow & 7;
  const int kswz  = (g ^ (c & 7)) * 8;        // K-frag chunk (dh 0..31)
  const int kswz2 = ((g + 4) ^ (c & 7)) * 8;  // K-frag chunk (dh 32..63)

  for (int t0 = 0; t0 < 2048; t0 += 64) {
    const u16* kg = Kb + (size_t)(t0 + srow) * 64;
    const u16* vg = Vb + (size_t)srow * 2048 + t0;
    short8 k0 = *reinterpret_cast<const short8*>(kg + sch * 8);
    short8 k1 = *reinterpret_cast<const short8*>(kg + (sch + 4) * 8);
    short8 v0 = *reinterpret_cast<const short8*>(vg + sch * 8);
    short8 v1 = *reinterpret_cast<const short8*>(vg + (sch + 4) * 8);
    __syncthreads();  // prior tile's LDS reads complete
    *reinterpret_cast<short8*>(&Kt[srow * 64 + ((sch ^ swz) * 8)]) = k0;
    *reinterpret_cast<short8*>(&Kt[srow * 64 + (((sch + 4) ^ swz) * 8)]) = k1;
    *reinterpret_cast<short8*>(&Vl[srow * 64 + ((sch ^ swz) * 8)]) = v0;
    *reinterpret_cast<short8*>(&Vl[srow * 64 + (((sch + 4) ^ swz) * 8)]) = v1;
    __syncthreads();

    #pragma unroll
    for (int cp = 0; cp < 2; cp++) {   // two 32-t chunk pairs per tile
      // QK^T swapped: S^T[t][q] for halves h=0,1 (t = cp*32 + h*16 + g*4+r)
      f32x4 sv[2][2];
      #pragma unroll
      for (int h = 0; h < 2; h++) {
        const u16* kr = Kt + (cp * 32 + h * 16 + c) * 64;
        short8 ka  = *reinterpret_cast<const short8*>(kr + kswz);
        short8 ka2 = *reinterpret_cast<const short8*>(kr + kswz2);
        #pragma unroll
        for (int qt = 0; qt < 2; qt++) {
          f32x4 z = (f32x4){0.f, 0.f, 0.f, 0.f};
          z = __builtin_amdgcn_mfma_f32_16x16x32_bf16(ka, bq[qt][0], z, 0, 0, 0);
          z = __builtin_amdgcn_mfma_f32_16x16x32_bf16(ka2, bq[qt][1], z, 0, 0, 0);
          sv[qt][h] = z;
        }
      }

      short8 pk[2];
      #pragma unroll
      for (int qt = 0; qt < 2; qt++) {
        float f[8];
        #pragma unroll
        for (int h = 0; h < 2; h++)
          #pragma unroll
          for (int r = 0; r < 4; r++)
            f[h * 4 + r] = sv[qt][h][r] * ksc;
        float mt = fmaxf(fmaxf(fmaxf(f[0], f[1]), fmaxf(f[2], f[3])),
                         fmaxf(fmaxf(f[4], f[5]), fmaxf(f[6], f[7])));
        mt = fmaxf(mt, __shfl_xor(mt, 16));
        mt = fmaxf(mt, __shfl_xor(mt, 32));
        // defer-max (T13): rescale only if max grew by > 8 (log2 domain)
        if (!__all(mt <= m_run[qt] + 8.f)) {
          const float mnew = fmaxf(m_run[qt], mt);
          const float alpha = exp2f(m_run[qt] - mnew);
          m_run[qt] = mnew;
          l_run[qt] *= alpha;
          float aw[4];
          #pragma unroll
          for (int r = 0; r < 4; r++) aw[r] = __shfl(alpha, g * 4 + r);
          #pragma unroll
          for (int dt = 0; dt < 4; dt++)
            #pragma unroll
            for (int r = 0; r < 4; r++) acc[qt][dt][r] *= aw[r];
        }
        float ps = 0.f;
        float p[8];
        #pragma unroll
        for (int i = 0; i < 8; i++) {
          p[i] = exp2f(f[i] - m_run[qt]);
          ps += p[i];
        }
        l_run[qt] += ps;
        #pragma unroll
        for (int i = 0; i < 8; i++)
          pk[qt][i] = (short)__builtin_bit_cast(u16, __float2bfloat16(p[i]));
      }

      // PV: A = P (in regs), B = V^T rows from LDS (two 8B halves per frag)
      #pragma unroll
      for (int dt = 0; dt < 4; dt++) {
        const u16* vr = Vl + (dt * 16 + c) * 64;
        const int ch0 = cp * 4 + (g >> 1);
        const int sub = (g & 1) * 4;
        short4v va = *reinterpret_cast<const short4v*>(vr + ((ch0 ^ (c & 7)) * 8) + sub);
        short4v vb2 = *reinterpret_cast<const short4v*>(vr + (((ch0 + 2) ^ (c & 7)) * 8) + sub);
        short8 vf = __builtin_shufflevector(va, vb2, 0, 1, 2, 3, 4, 5, 6, 7);
        acc[0][dt] = __builtin_amdgcn_mfma_f32_16x16x32_bf16(pk[0], vf, acc[0][dt], 0, 0, 0);
        acc[1][dt] = __builtin_amdgcn_mfma_f32_16x16x32_bf16(pk[1], vf, acc[1][dt], 0, 0, 0);
      }
    }
  }

  // finalize: full row-sum, then per-output-row 1/l broadcast
  u16* ob = ao + (size_t)(bh >> 4) * 2048 * 1024 + (bh & 15) * 64;
  #pragma unroll
  for (int qt = 0; qt < 2; qt++) {
    float l = l_run[qt];
    l += __shfl_xor(l, 16);
    l += __shfl_xor(l, 32);
    float lq[4];
    #pragma unroll
    for (int r = 0; r < 4; r++) lq[r] = 1.0f / __shfl(l, g * 4 + r);
    #pragma unroll
    for (int dt = 0; dt < 4; dt++)
      #pragma unroll
      for (int r = 0; r < 4; r++) {
        const size_t q = qbase + qt * 16 + g * 4 + r;
        ob[q * 1024 + dt * 16 + c] = f2bf(acc[qt][dt][r] * lq[r]);
      }
  }
}

extern "C" void kernel_launch(void* const* d_in, const int* in_sizes, int n_in,
                              void* d_out, int out_size, void* d_ws, size_t ws_size,
                              hipStream_t stream) {
  const float* embed = (const float*)d_in[0];
  const float* Wq = (const float*)d_in[1];
  const float* Wk = (const float*)d_in[2];
  const float* Wv = (const float*)d_in[3];
  const float* bv = (const float*)d_in[4];
  const float* W1 = (const float*)d_in[5];
  const float* b1 = (const float*)d_in[6];
  const float* W2 = (const float*)d_in[7];
  const float* b2 = (const float*)d_in[8];

  char* ws = (char*)d_ws;
  u16* ebf = (u16*)ws;  ws += (size_t)4096 * 1024 * 2;  // embed bf16 [B*S, D]
  u16* wqb = (u16*)ws;  ws += (size_t)1024 * 1024 * 2;
  u16* wkb = (u16*)ws;  ws += (size_t)1024 * 1024 * 2;
  u16* wvb = (u16*)ws;  ws += (size_t)1024 * 1024 * 2;
  u16* w1b = (u16*)ws;  ws += (size_t)2048 * 1024 * 2;
  u16* w2b = (u16*)ws;  ws += (size_t)1024 * 2048 * 2;
  u16* Qh  = (u16*)ws;  ws += (size_t)4096 * 1024 * 2;  // [B,H,S,DH]
  u16* Kh  = (u16*)ws;  ws += (size_t)4096 * 1024 * 2;  // [B,H,S,DH]
  u16* Vt  = (u16*)ws;  ws += (size_t)4096 * 1024 * 2;  // [B,H,DH,S]
  u16* ao  = (u16*)ws;  ws += (size_t)4096 * 1024 * 2;  // attn out bf16 [B*S, D]
  u16* h1  = (u16*)ws;  ws += (size_t)4096 * 2048 * 2;  // FFN hidden bf16 [B*S, 2D]

  auto cvt = [&](const float* s, u16* d, int n) {
    int n4 = n / 4;
    f32_to_bf16<<<dim3((n4 + 255) / 256), dim3(256), 0, stream>>>(s, d, n4);
  };
  cvt(embed, ebf, 4096 * 1024);
  cvt(Wq, wqb, 1024 * 1024);
  cvt(Wk, wkb, 1024 * 1024);
  cvt(Wv, wvb, 1024 * 1024);
  cvt(W1, w1b, 2048 * 1024);
  cvt(W2, w2b, 2048 * 1024);

  dim3 blk(256);
  gemm_bt<0><<<dim3(8, 32), blk, 0, stream>>>(ebf, wqb, nullptr, nullptr, Qh, 4096, 1024, 1024);
  gemm_bt<0><<<dim3(8, 32), blk, 0, stream>>>(ebf, wkb, nullptr, nullptr, Kh, 4096, 1024, 1024);
  gemm_bt<2><<<dim3(8, 32), blk, 0, stream>>>(ebf, wvb, bv, nullptr, Vt, 4096, 1024, 1024);
  attn_kernel<<<dim3(16, 32), blk, 0, stream>>>(Qh, Kh, Vt, ao);
  gemm_bt<3><<<dim3(16, 32), blk, 0, stream>>>(ao, w1b, b1, nullptr, h1, 4096, 2048, 1024);
  gemm_bt<4><<<dim3(8, 32), blk, 0, stream>>>(h1, w2b, b2, embed, d_out, 4096, 1024, 2048);
}